// Round 13
// baseline (1343.504 us; speedup 1.0000x reference)
//
#include <hip/hip_runtime.h>
#include <hip/hip_bf16.h>

// Problem constants (from setup_inputs)
#define NROWS 131072
#define DIN   512
#define HDIM  128
#define EDIM  32
#define KCODES 512

// ---- DIAGNOSTIC ROUND 2: REPS wrappers (R8 technique) on the R12 kernels +
// k_xsum = pure coalesced X-read BW probe. Outputs bit-identical to REPS=1:
// rep>0 accumulators go to dummy scratch; H1/topics rewritten identically.
#define REPS_G 5
#define REPS_E 8
#define REPS_R 5
#define REPS_X 5

typedef unsigned short ushort_t;
typedef unsigned int   uint_t;
typedef float f32x4 __attribute__((ext_vector_type(4)));
typedef short s16x8 __attribute__((ext_vector_type(8)));

// ---------- bf16 helpers ----------
__device__ __forceinline__ float bflo(uint_t u) {
  union { uint_t u; float f; } x; x.u = u << 16; return x.f;
}
__device__ __forceinline__ float bfhi(uint_t u) {
  union { uint_t u; float f; } x; x.u = u & 0xffff0000u; return x.f;
}
__device__ __forceinline__ ushort_t f2bf(float f) {   // RNE (off hot path)
  union { float f; uint_t u; } x; x.f = f;
  uint_t u = x.u;
  return (ushort_t)((u + 0x7fffu + ((u >> 16) & 1u)) >> 16);
}
// pack-truncate 2 fp32 -> (bf16(hi)<<16)|bf16(lo) in ONE v_perm_b32.
__device__ __forceinline__ uint_t pk2(float lo, float hi) {
  return __builtin_amdgcn_perm(__float_as_uint(hi), __float_as_uint(lo), 0x07060302u);
}

// ---------------------------------------------------------------------------
// k_prep (unchanged from R12, fixed offsets)
// ---------------------------------------------------------------------------
__global__ __launch_bounds__(256) void k_prep(
    const float* __restrict__ W1, const float* __restrict__ W2,
    const float* __restrict__ CB, const float* __restrict__ dW1,
    const float* __restrict__ db1,
    ushort_t* __restrict__ W1f, ushort_t* __restrict__ W2t,
    ushort_t* __restrict__ CBb, float* __restrict__ cn,
    float* __restrict__ T, float* __restrict__ accz)
{
  int gid = blockIdx.x * 256 + threadIdx.x;   // 0..65535
  {
    int t = gid >> 9, lane = (gid >> 3) & 63, j = gid & 7;
    int c16 = t >> 4, kk = t & 15, lr = lane & 15, lk = lane >> 4;
    W1f[gid] = f2bf(W1[(kk * 32 + lk * 8 + j) * 128 + c16 * 16 + lr]);
  }
  {
    int k = gid >> 7, j = gid & 127;          // T[k][j], 512x128
    float acc = db1[j];
#pragma unroll
    for (int e = 0; e < EDIM; ++e) acc += CB[k * EDIM + e] * dW1[e * HDIM + j];
    T[gid] = acc;
  }
  if (gid < 16384) CBb[gid] = f2bf(CB[gid]);
  if (gid < 4096) {
    int e = gid >> 7, k = gid & 127;
    W2t[gid] = f2bf(W2[k * 32 + e]);
  }
  if (gid < 512) {
    float s = 0.f;
#pragma unroll
    for (int e = 0; e < EDIM; ++e) { float c = CB[gid * EDIM + e]; s += c * c; }
    cn[gid] = s;
  }
  if (gid < 2816) accz[gid] = 0.f;
}

// ---------------------------------------------------------------------------
// k_xsum: THE probe. Pure coalesced grid-stride read of X (canonical max-BW
// pattern), REPS_X passes. Tells us the achievable X-read bandwidth.
// grid 2048 x 256, tiny VGPR, 8 blocks/CU.
// ---------------------------------------------------------------------------
__global__ __launch_bounds__(256, 8) void k_xsum(
    const float* __restrict__ X, float* __restrict__ dumX)
{
  const f32x4* X4 = (const f32x4*)X;
  const size_t nvec = (size_t)NROWS * DIN / 4;       // 16,777,216
  const size_t stride = (size_t)gridDim.x * 256;
  float acc = 0.f;
  for (int rep = 0; rep < REPS_X; ++rep) {
    for (size_t j = (size_t)blockIdx.x * 256 + threadIdx.x; j < nvec; j += stride) {
      f32x4 v = X4[j];
      acc += v[0] + v[1] + v[2] + v[3];
    }
  }
#pragma unroll
  for (int off = 32; off > 0; off >>= 1) acc += __shfl_down(acc, off, 64);
  if ((threadIdx.x & 63) == 0) atomicAdd(dumX, acc);
}

// ---------------------------------------------------------------------------
// K1 (R12 contiguous-read structure, REPS_G wrapper)
// ---------------------------------------------------------------------------
__global__ __launch_bounds__(256, 4) void k_gemm1(
    const float* __restrict__ X, const ushort_t* __restrict__ W1f,
    const float* __restrict__ b1, ushort_t* __restrict__ H1,
    float* __restrict__ colsumR, float* __restrict__ colsumsqR,
    float* __restrict__ dumA, float* __restrict__ dumB)
{
  __shared__ ushort_t Ab[32 * 512];
  __shared__ float lsum[128], lssq[128];
  const int tid = threadIdx.x;
  const int lane = tid & 63;
  const int wid = tid >> 6;
  const int lr = lane & 15;
  const int lk = lane >> 4;
  const size_t row0 = (size_t)blockIdx.x * 32;

  for (int rep = 0; rep < REPS_G; ++rep) {
    float* csT = (rep == 0) ? colsumR : dumA;
    float* cqT = (rep == 0) ? colsumsqR : dumB;
    __syncthreads();                       // prev rep done with Ab / lsum
    if (tid < 128) { lsum[tid] = 0.f; lssq[tid] = 0.f; }

    // stage: fully contiguous 64KB block read
#pragma unroll
    for (int i = 0; i < 16; ++i) {
      int f = tid + 256 * i;
      int row = f >> 7, s = f & 127;
      float4 v = *(const float4*)(X + row0 * 512 + (size_t)f * 4);
      uint2 p; p.x = pk2(v.x, v.y); p.y = pk2(v.z, v.w);
      int c = s >> 1, h = s & 1;
      *(uint2*)(&Ab[row * 512 + (((c ^ (row & 7)) << 3) + h * 4)]) = p;
    }
    __syncthreads();

    f32x4 acc[2][2];
#pragma unroll
    for (int i = 0; i < 2; ++i)
#pragma unroll
      for (int j = 0; j < 2; ++j) acc[i][j] = (f32x4)(0.f);

#pragma unroll
    for (int ks = 0; ks < 16; ++ks) {
      s16x8 af[2], bf[2];
#pragma unroll
      for (int mf = 0; mf < 2; ++mf) {
        int row = mf * 16 + lr;
        int c = ks * 4 + lk;
        af[mf] = *(const s16x8*)(&Ab[row * 512 + ((c ^ (row & 7)) << 3)]);
      }
#pragma unroll
      for (int nf = 0; nf < 2; ++nf)
        bf[nf] = *(const s16x8*)(W1f + ((((wid * 2 + nf) * 16 + ks) << 9) + lane * 8));
#pragma unroll
      for (int mf = 0; mf < 2; ++mf)
#pragma unroll
        for (int nf = 0; nf < 2; ++nf)
          acc[mf][nf] = __builtin_amdgcn_mfma_f32_16x16x32_bf16(
              af[mf], bf[nf], acc[mf][nf], 0, 0, 0);
    }
    __syncthreads();

    float bv[2]; int col[2];
#pragma unroll
    for (int nf = 0; nf < 2; ++nf) {
      col[nf] = wid * 32 + nf * 16 + lr;
      bv[nf] = b1[col[nf]];
    }
    float s[2] = {0.f, 0.f}, ss[2] = {0.f, 0.f};
    ushort_t* Elds = Ab;
#pragma unroll
    for (int mf = 0; mf < 2; ++mf) {
#pragma unroll
      for (int r = 0; r < 4; ++r) {
        int row = mf * 16 + lk * 4 + r;
#pragma unroll
        for (int nf = 0; nf < 2; ++nf) {
          float hv = acc[mf][nf][r] + bv[nf];
          s[nf] += hv; ss[nf] += hv * hv;
          Elds[row * 136 + col[nf]] = f2bf(hv);
        }
      }
    }
    __syncthreads();
#pragma unroll
    for (int i = 0; i < 2; ++i) {
      int idx = tid + 256 * i;
      int row = idx >> 4, seg = idx & 15;
      uint4 v = *(const uint4*)(&Elds[row * 136 + seg * 8]);
      *(uint4*)(H1 + (row0 + row) * 128 + seg * 8) = v;
    }
#pragma unroll
    for (int nf = 0; nf < 2; ++nf) {
      atomicAdd(&lsum[col[nf]], s[nf]);
      atomicAdd(&lssq[col[nf]], ss[nf]);
    }
    __syncthreads();
    if (tid < 128) {
      int part = blockIdx.x & 7;
      atomicAdd(&csT[part * 128 + tid], lsum[tid]);
      atomicAdd(&cqT[part * 128 + tid], lssq[tid]);
    }
  }
}

// ---------------------------------------------------------------------------
// BN params for encoder (sums the 8 replicated partials)
// ---------------------------------------------------------------------------
__global__ void k_bn1(const float* __restrict__ colsumR,
                      const float* __restrict__ colsumsqR,
                      const float* __restrict__ g, const float* __restrict__ be,
                      float* __restrict__ scale, float* __restrict__ shift)
{
  int j = threadIdx.x;
  float cs = 0.f, cq = 0.f;
#pragma unroll
  for (int p = 0; p < 8; ++p) {
    cs += colsumR[p * 128 + j];
    cq += colsumsqR[p * 128 + j];
  }
  float mu = cs * (1.f / NROWS);
  float var = cq * (1.f / NROWS) - mu * mu;
  float sc = g[j] * rsqrtf(var + 1e-5f);
  scale[j] = sc;
  shift[j] = be[j] - mu * sc;
}

// ---------------------------------------------------------------------------
// K3 (frozen structure, REPS_E wrapper)
// ---------------------------------------------------------------------------
__global__ __launch_bounds__(256, 4) void k_encode(
    const ushort_t* __restrict__ H1, const float* __restrict__ scale1,
    const float* __restrict__ shift1, const ushort_t* __restrict__ W2t,
    const float* __restrict__ b2, const ushort_t* __restrict__ CBb,
    const float* __restrict__ cn, int* __restrict__ topics,
    int* __restrict__ counts, float* __restrict__ Zloss,
    int* __restrict__ dumCounts, float* __restrict__ dumZ)
{
  __shared__ ushort_t Hb[64 * 128];
  __shared__ float Zt[64 * 33];
  __shared__ int hist[512];
  __shared__ float zsh;

  const int tid = threadIdx.x;
  const int lane = tid & 63;
  const int w = tid >> 6;
  const int lr = lane & 15;
  const int lk = lane >> 4;
  const int row0 = blockIdx.x * 64;

  for (int rep = 0; rep < REPS_E; ++rep) {
    int* cntT = (rep == 0) ? counts : dumCounts;
    float* zlT = (rep == 0) ? Zloss : dumZ;
    __syncthreads();
    hist[tid] = 0; hist[tid + 256] = 0;
    if (tid == 0) zsh = 0.f;

    {
      const int c8 = (tid & 15) * 8;
      const int rb = tid >> 4;
      float sc[8], sh[8];
      {
        float4 a = *(const float4*)(scale1 + c8);
        float4 b = *(const float4*)(scale1 + c8 + 4);
        sc[0]=a.x; sc[1]=a.y; sc[2]=a.z; sc[3]=a.w; sc[4]=b.x; sc[5]=b.y; sc[6]=b.z; sc[7]=b.w;
        float4 e = *(const float4*)(shift1 + c8);
        float4 f = *(const float4*)(shift1 + c8 + 4);
        sh[0]=e.x; sh[1]=e.y; sh[2]=e.z; sh[3]=e.w; sh[4]=f.x; sh[5]=f.y; sh[6]=f.z; sh[7]=f.w;
      }
#pragma unroll
      for (int j = 0; j < 4; ++j) {
        int r = rb + 16 * j;
        uint4 v = *(const uint4*)(H1 + (size_t)(row0 + r) * HDIM + c8);
        uint_t u[4] = {v.x, v.y, v.z, v.w};
        uint4 o;
        uint_t* op = (uint_t*)&o;
#pragma unroll
        for (int m = 0; m < 4; ++m) {
          float f0 = fmaxf(bflo(u[m]) * sc[2*m]   + sh[2*m],   0.f);
          float f1 = fmaxf(bfhi(u[m]) * sc[2*m+1] + sh[2*m+1], 0.f);
          op[m] = pk2(f0, f1);
        }
        *(uint4*)(Hb + r * 128 + ((((c8 >> 3) ^ (r & 7))) << 3)) = o;
      }
    }
    __syncthreads();

    float zn4[4];
    {
      s16x8 af[4];
#pragma unroll
      for (int kt = 0; kt < 4; ++kt) {
        int m = w * 16 + lr;
        int b = kt * 4 + lk;
        af[kt] = *(const s16x8*)(Hb + m * 128 + ((b ^ (m & 7)) << 3));
      }
      f32x4 zacc[2];
      zacc[0] = (f32x4)(0.f); zacc[1] = (f32x4)(0.f);
#pragma unroll
      for (int ct = 0; ct < 2; ++ct)
#pragma unroll
        for (int kt = 0; kt < 4; ++kt) {
          s16x8 bf = *(const s16x8*)(W2t + (ct * 16 + lr) * 128 + kt * 32 + lk * 8);
          zacc[ct] = __builtin_amdgcn_mfma_f32_16x16x32_bf16(af[kt], bf, zacc[ct], 0, 0, 0);
        }
      float bias0 = b2[lr], bias1 = b2[16 + lr];
      float s4[4];
#pragma unroll
      for (int r = 0; r < 4; ++r) {
        float z0 = zacc[0][r] + bias0;
        float z1 = zacc[1][r] + bias1;
        int row = w * 16 + lk * 4 + r;
        Zt[row * 33 + lr] = z0;
        Zt[row * 33 + 16 + lr] = z1;
        s4[r] = z0 * z0 + z1 * z1;
      }
#pragma unroll
      for (int m = 1; m < 16; m <<= 1) {
#pragma unroll
        for (int r = 0; r < 4; ++r) s4[r] += __shfl_xor(s4[r], m, 64);
      }
#pragma unroll
      for (int r = 0; r < 4; ++r) zn4[r] = s4[r];
    }
    __syncthreads();

    {
      s16x8 za;
      {
        const float* zp = Zt + (w * 16 + lr) * 33 + lk * 8;
        float4 q0 = *(const float4*)(zp);
        float4 q1 = *(const float4*)(zp + 4);
        union { s16x8 v; uint_t u[4]; } zu;
        zu.u[0] = pk2(q0.x, q0.y);
        zu.u[1] = pk2(q0.z, q0.w);
        zu.u[2] = pk2(q1.x, q1.y);
        zu.u[3] = pk2(q1.z, q1.w);
        za = zu.v;
      }
      float minv[4] = {3.4e38f, 3.4e38f, 3.4e38f, 3.4e38f};
      int mini[4] = {0, 0, 0, 0};
#pragma unroll 4
      for (int t = 0; t < 32; ++t) {
        const int c = t * 16 + lr;
        s16x8 cb = *(const s16x8*)(CBb + c * 32 + lk * 8);
        f32x4 dot = __builtin_amdgcn_mfma_f32_16x16x32_bf16(za, cb, (f32x4)(0.f), 0, 0, 0);
        float cnv = cn[c];
#pragma unroll
        for (int r = 0; r < 4; ++r) {
          float d = fmaf(-2.f, dot[r], cnv);
          if (d < minv[r]) { minv[r] = d; mini[r] = c; }
        }
      }
#pragma unroll
      for (int m = 1; m < 16; m <<= 1) {
#pragma unroll
        for (int r = 0; r < 4; ++r) {
          float ov = __shfl_xor(minv[r], m, 64);
          int   oi = __shfl_xor(mini[r], m, 64);
          if (ov < minv[r] || (ov == minv[r] && oi < mini[r])) { minv[r] = ov; mini[r] = oi; }
        }
      }
      if (lr == 0) {
        float part = 0.f;
#pragma unroll
        for (int r = 0; r < 4; ++r) {
          int row = row0 + w * 16 + lk * 4 + r;
          topics[row] = mini[r];
          atomicAdd(&hist[mini[r]], 1);
          part += minv[r] + zn4[r];
        }
        atomicAdd(&zsh, part);
      }
    }
    __syncthreads();
    {
      int h0 = hist[tid], h1 = hist[tid + 256];
      if (h0) atomicAdd(&cntT[tid], h0);
      if (h1) atomicAdd(&cntT[tid + 256], h1);
      if (tid == 0) atomicAdd(zlT, zsh);
    }
  }
}

// Decoder BN params from topic histogram (exact batch stats)
__global__ void k_bn2(const int* __restrict__ counts, const float* __restrict__ T,
    const float* __restrict__ g, const float* __restrict__ be,
    float* __restrict__ scale2, float* __restrict__ shift2)
{
  __shared__ float cw[512];
  int j = threadIdx.x;  // 128
  for (int i = j; i < 512; i += 128) cw[i] = (float)counts[i];
  __syncthreads();
  float s = 0.f, ss = 0.f;
  for (int k = 0; k < KCODES; ++k) {
    float t = T[k * HDIM + j];
    float c = cw[k];
    s += c * t; ss += c * t * t;
  }
  float mu = s * (1.f / NROWS);
  float var = ss * (1.f / NROWS) - mu * mu;
  float sc = g[j] * rsqrtf(var + 1e-5f);
  scale2[j] = sc;
  shift2[j] = be[j] - mu * sc;
}

// U = relu(bn(T)) @ dec_W2 + dec_b2   [512 x 512]
__global__ __launch_bounds__(256) void k_U(const float* __restrict__ T,
    const float* __restrict__ scale2, const float* __restrict__ shift2,
    const float* __restrict__ dW2, const float* __restrict__ db2,
    float* __restrict__ U)
{
  __shared__ float Tb[128];
  const int tid = threadIdx.x;
  const int k = blockIdx.x >> 1;
  const int c = (blockIdx.x & 1) * 256 + tid;
  if (tid < 128) Tb[tid] = fmaxf(T[k * HDIM + tid] * scale2[tid] + shift2[tid], 0.f);
  __syncthreads();
  float acc = db2[c];
#pragma unroll 8
  for (int j = 0; j < HDIM; ++j) acc += Tb[j] * dW2[j * 512 + c];
  U[(size_t)k * 512 + c] = acc;
}

// ---------------------------------------------------------------------------
// Reconstruction (R12 broadcast structure, REPS_R wrapper)
// ---------------------------------------------------------------------------
__global__ __launch_bounds__(256, 4) void k_recon(
    const float* __restrict__ X, const float* __restrict__ U,
    const int* __restrict__ topics, float* __restrict__ Rsum,
    float* __restrict__ dumR)
{
  __shared__ float bsum;
  const int tid = threadIdx.x;
  const int lane = tid & 63;
  const int wave = blockIdx.x * 4 + (tid >> 6);    // 0..4095
  const size_t base = (size_t)wave * 32;

  for (int rep = 0; rep < REPS_R; ++rep) {
    float* rT = (rep == 0) ? Rsum : dumR;
    if (tid == 0) bsum = 0.f;
    __syncthreads();
    int tv = (lane < 32) ? topics[base + lane] : 0;
    const float4* Xb = (const float4*)(X + base * 512);
    float acc = 0.f;
#pragma unroll 4
    for (int i = 0; i < 32; ++i) {
      int t = __shfl(tv, i, 64);
      const float4* xr = Xb + i * 128;
      const float4* ur = (const float4*)(U + (size_t)t * 512);
      float4 x0 = xr[lane],      u0 = ur[lane];
      float4 x1 = xr[lane + 64], u1 = ur[lane + 64];
      float d;
      d = x0.x - u0.x; acc += d * d;
      d = x0.y - u0.y; acc += d * d;
      d = x0.z - u0.z; acc += d * d;
      d = x0.w - u0.w; acc += d * d;
      d = x1.x - u1.x; acc += d * d;
      d = x1.y - u1.y; acc += d * d;
      d = x1.z - u1.z; acc += d * d;
      d = x1.w - u1.w; acc += d * d;
    }
#pragma unroll
    for (int off = 32; off > 0; off >>= 1) acc += __shfl_down(acc, off, 64);
    if (lane == 0) atomicAdd(&bsum, acc);
    __syncthreads();
    if (tid == 0) atomicAdd(rT, bsum);
  }
}

__global__ void k_final(const float* __restrict__ Zloss,
                        const float* __restrict__ Rsum, float* __restrict__ out)
{
  // C_loss == Z_loss in forward (stop_gradient is identity forward)
  out[0] = 2.f * Zloss[0] + sqrtf(Rsum[0]);
}

// ---------------------------------------------------------------------------
// Workspace layout (bytes) — as R12 (fixed), plus diagnostic dummies @ 40 MB.
// ---------------------------------------------------------------------------
extern "C" void kernel_launch(void* const* d_in, const int* in_sizes, int n_in,
                              void* d_out, int out_size, void* d_ws, size_t ws_size,
                              hipStream_t stream) {
  const float* X    = (const float*)d_in[0];
  const float* eW1  = (const float*)d_in[1];
  const float* eb1  = (const float*)d_in[2];
  const float* eg1  = (const float*)d_in[3];
  const float* ebe1 = (const float*)d_in[4];
  const float* eW2  = (const float*)d_in[5];
  const float* eb2  = (const float*)d_in[6];
  const float* CB   = (const float*)d_in[7];
  const float* dW1  = (const float*)d_in[8];
  const float* db1  = (const float*)d_in[9];
  const float* dg1  = (const float*)d_in[10];
  const float* dbe1 = (const float*)d_in[11];
  const float* dW2  = (const float*)d_in[12];
  const float* db2  = (const float*)d_in[13];
  float* out = (float*)d_out;

  char* wsb = (char*)d_ws;
  ushort_t* H1    = (ushort_t*)wsb;
  int* topics     = (int*)(wsb + 33554432);
  float* colsumR  = (float*)(wsb + 34078720);
  float* colsumsqR= (float*)(wsb + 34078720 + 4096);
  int* counts     = (int*)(wsb + 34078720 + 8192);
  float* Zloss    = (float*)(wsb + 34078720 + 10240);
  float* Rsum     = Zloss + 1;
  float* scale1   = (float*)(wsb + 34092032);
  float* shift1   = scale1 + 128;
  float* cn       = (float*)(wsb + 34093056);
  float* T        = (float*)(wsb + 34095104);
  float* scale2   = (float*)(wsb + 34357248);
  float* shift2   = scale2 + 128;
  float* U        = (float*)(wsb + 34358272);
  ushort_t* W1f   = (ushort_t*)(wsb + 34358272);  // aliases U (disjoint lifetime)
  ushort_t* W2t   = (ushort_t*)(wsb + 35406848);
  ushort_t* CBb   = (ushort_t*)(wsb + 35415040);
  // diagnostic dummies @ 40 MB (never read, never zeroed)
  float* dumA     = (float*)(wsb + 41943040);          // 1024 f32
  float* dumB     = dumA + 1024;
  int*   dumCnt   = (int*)(wsb + 41943040 + 16384);
  float* dumZ     = (float*)(wsb + 41943040 + 20480);
  float* dumR     = dumZ + 1;
  float* dumX     = dumZ + 2;

  k_prep<<<256, 256, 0, stream>>>(eW1, eW2, CB, dW1, db1, W1f, W2t, CBb, cn, T,
                                  colsumR);
  k_xsum<<<2048, 256, 0, stream>>>(X, dumX);
  k_gemm1<<<NROWS / 32, 256, 0, stream>>>(X, W1f, eb1, H1, colsumR, colsumsqR,
                                          dumA, dumB);
  k_bn1<<<1, 128, 0, stream>>>(colsumR, colsumsqR, eg1, ebe1, scale1, shift1);
  k_encode<<<NROWS / 64, 256, 0, stream>>>(H1, scale1, shift1, W2t, eb2, CBb, cn,
                                           topics, counts, Zloss, dumCnt, dumZ);
  k_bn2<<<1, 128, 0, stream>>>(counts, T, dg1, dbe1, scale2, shift2);
  k_U<<<KCODES * 2, 256, 0, stream>>>(T, scale2, shift2, dW2, db2, U);
  k_recon<<<1024, 256, 0, stream>>>(X, U, topics, Rsum, dumR);
  k_final<<<1, 1, 0, stream>>>(Zloss, Rsum, out);
}

// Round 14
// 230.720 us; speedup vs baseline: 5.8231x; 5.8231x over previous
//
#include <hip/hip_runtime.h>
#include <hip/hip_bf16.h>

// Problem constants (from setup_inputs)
#define NROWS 131072
#define DIN   512
#define HDIM  128
#define EDIM  32
#define KCODES 512

typedef unsigned short ushort_t;
typedef unsigned int   uint_t;
typedef float f32x4 __attribute__((ext_vector_type(4)));
typedef short s16x8 __attribute__((ext_vector_type(8)));

// ---------- bf16 helpers ----------
__device__ __forceinline__ float bflo(uint_t u) {
  union { uint_t u; float f; } x; x.u = u << 16; return x.f;
}
__device__ __forceinline__ float bfhi(uint_t u) {
  union { uint_t u; float f; } x; x.u = u & 0xffff0000u; return x.f;
}
__device__ __forceinline__ ushort_t f2bf(float f) {   // RNE (off hot path)
  union { float f; uint_t u; } x; x.f = f;
  uint_t u = x.u;
  return (ushort_t)((u + 0x7fffu + ((u >> 16) & 1u)) >> 16);
}
// pack-truncate 2 fp32 -> (bf16(hi)<<16)|bf16(lo) in ONE v_perm_b32.
__device__ __forceinline__ uint_t pk2(float lo, float hi) {
  return __builtin_amdgcn_perm(__float_as_uint(hi), __float_as_uint(lo), 0x07060302u);
}

// ---------------------------------------------------------------------------
// k_prep (unchanged from R12)
// ---------------------------------------------------------------------------
__global__ __launch_bounds__(256) void k_prep(
    const float* __restrict__ W1, const float* __restrict__ W2,
    const float* __restrict__ CB, const float* __restrict__ dW1,
    const float* __restrict__ db1,
    ushort_t* __restrict__ W1f, ushort_t* __restrict__ W2t,
    ushort_t* __restrict__ CBb, float* __restrict__ cn,
    float* __restrict__ T, float* __restrict__ accz)
{
  int gid = blockIdx.x * 256 + threadIdx.x;   // 0..65535
  {
    int t = gid >> 9, lane = (gid >> 3) & 63, j = gid & 7;
    int c16 = t >> 4, kk = t & 15, lr = lane & 15, lk = lane >> 4;
    W1f[gid] = f2bf(W1[(kk * 32 + lk * 8 + j) * 128 + c16 * 16 + lr]);
  }
  {
    int k = gid >> 7, j = gid & 127;          // T[k][j], 512x128
    float acc = db1[j];
#pragma unroll
    for (int e = 0; e < EDIM; ++e) acc += CB[k * EDIM + e] * dW1[e * HDIM + j];
    T[gid] = acc;
  }
  if (gid < 16384) CBb[gid] = f2bf(CB[gid]);
  if (gid < 4096) {
    int e = gid >> 7, k = gid & 127;
    W2t[gid] = f2bf(W2[k * 32 + e]);
  }
  if (gid < 512) {
    float s = 0.f;
#pragma unroll
    for (int e = 0; e < EDIM; ++e) { float c = CB[gid * EDIM + e]; s += c * c; }
    cn[gid] = s;
  }
  if (gid < 2816) accz[gid] = 0.f;  // counts/Zloss/Rsum region (and legacy)
}

// ---------------------------------------------------------------------------
// K1 (R12 contiguous-read structure; ATOMIC-FREE stats):
// column sums reduced in-wave via shfl_xor(16/32), then ONE coalesced
// non-atomic partial write per block: colsump[b][128], colsumsqp[b][128].
// No stats LDS, no global atomics (was 1.05M device atomics -> ~90MB RMW).
// ---------------------------------------------------------------------------
__global__ __launch_bounds__(256, 4) void k_gemm1(
    const float* __restrict__ X, const ushort_t* __restrict__ W1f,
    const float* __restrict__ b1, ushort_t* __restrict__ H1,
    float* __restrict__ colsump, float* __restrict__ colsumsqp)
{
  __shared__ ushort_t Ab[32 * 512];    // 32 KB bf16 A, chunk-swizzled
  const int tid = threadIdx.x;
  const int lane = tid & 63;
  const int wid = tid >> 6;
  const int lr = lane & 15;
  const int lk = lane >> 4;
  const size_t row0 = (size_t)blockIdx.x * 32;

  // ---- stage: fully contiguous 64KB block read
#pragma unroll
  for (int i = 0; i < 16; ++i) {
    int f = tid + 256 * i;
    int row = f >> 7, s = f & 127;
    float4 v = *(const float4*)(X + row0 * 512 + (size_t)f * 4);
    uint2 p; p.x = pk2(v.x, v.y); p.y = pk2(v.z, v.w);
    int c = s >> 1, h = s & 1;
    *(uint2*)(&Ab[row * 512 + (((c ^ (row & 7)) << 3) + h * 4)]) = p;
  }
  __syncthreads();

  f32x4 acc[2][2];
#pragma unroll
  for (int i = 0; i < 2; ++i)
#pragma unroll
    for (int j = 0; j < 2; ++j) acc[i][j] = (f32x4)(0.f);

#pragma unroll
  for (int ks = 0; ks < 16; ++ks) {
    s16x8 af[2], bf[2];
#pragma unroll
    for (int mf = 0; mf < 2; ++mf) {
      int row = mf * 16 + lr;
      int c = ks * 4 + lk;
      af[mf] = *(const s16x8*)(&Ab[row * 512 + ((c ^ (row & 7)) << 3)]);
    }
#pragma unroll
    for (int nf = 0; nf < 2; ++nf)
      bf[nf] = *(const s16x8*)(W1f + ((((wid * 2 + nf) * 16 + ks) << 9) + lane * 8));
#pragma unroll
    for (int mf = 0; mf < 2; ++mf)
#pragma unroll
      for (int nf = 0; nf < 2; ++nf)
        acc[mf][nf] = __builtin_amdgcn_mfma_f32_16x16x32_bf16(
            af[mf], bf[nf], acc[mf][nf], 0, 0, 0);
  }
  __syncthreads();   // all A-reads done before LDS reuse

  // ---- epilogue: bias + per-lane stats; Elds transpose -> coalesced H1
  float bv[2]; int col[2];
#pragma unroll
  for (int nf = 0; nf < 2; ++nf) {
    col[nf] = wid * 32 + nf * 16 + lr;
    bv[nf] = b1[col[nf]];
  }
  float s[2] = {0.f, 0.f}, ss[2] = {0.f, 0.f};
  ushort_t* Elds = Ab;   // 32 x 136 bf16 = 8.7 KB (reuse)
#pragma unroll
  for (int mf = 0; mf < 2; ++mf) {
#pragma unroll
    for (int r = 0; r < 4; ++r) {
      int row = mf * 16 + lk * 4 + r;
#pragma unroll
      for (int nf = 0; nf < 2; ++nf) {
        float hv = acc[mf][nf][r] + bv[nf];
        s[nf] += hv; ss[nf] += hv * hv;
        Elds[row * 136 + col[nf]] = f2bf(hv);
      }
    }
  }
  __syncthreads();
  // copy out 32 rows x 128 bf16 (512 uint4), fully coalesced
#pragma unroll
  for (int i = 0; i < 2; ++i) {
    int idx = tid + 256 * i;
    int row = idx >> 4, seg = idx & 15;
    uint4 v = *(const uint4*)(&Elds[row * 136 + seg * 8]);
    *(uint4*)(H1 + (row0 + row) * 128 + seg * 8) = v;
  }
  // column sums: reduce the 4 lanes (lk=0..3) sharing each col via shfl,
  // then one coalesced per-block write (NO atomics).
#pragma unroll
  for (int nf = 0; nf < 2; ++nf) {
    s[nf]  += __shfl_xor(s[nf], 16, 64);
    s[nf]  += __shfl_xor(s[nf], 32, 64);
    ss[nf] += __shfl_xor(ss[nf], 16, 64);
    ss[nf] += __shfl_xor(ss[nf], 32, 64);
  }
  if (lane < 16) {
    size_t bb = (size_t)blockIdx.x * 128;
#pragma unroll
    for (int nf = 0; nf < 2; ++nf) {
      colsump[bb + wid * 32 + nf * 16 + lane]   = s[nf];
      colsumsqp[bb + wid * 32 + nf * 16 + lane] = ss[nf];
    }
  }
}

// ---------------------------------------------------------------------------
// BN params for encoder: tree-reduce the 4096 per-block partials.
// grid 128 (one block per column j), 256 threads.
// ---------------------------------------------------------------------------
__global__ __launch_bounds__(256) void k_bn1(
    const float* __restrict__ colsump, const float* __restrict__ colsumsqp,
    const float* __restrict__ g, const float* __restrict__ be,
    float* __restrict__ scale, float* __restrict__ shift)
{
  __shared__ float wcs[4], wcq[4];
  const int j = blockIdx.x;
  const int tid = threadIdx.x;
  float cs = 0.f, cq = 0.f;
#pragma unroll
  for (int i = 0; i < 16; ++i) {
    size_t b = (size_t)(tid + 256 * i) * 128 + j;
    cs += colsump[b];
    cq += colsumsqp[b];
  }
#pragma unroll
  for (int off = 32; off > 0; off >>= 1) {
    cs += __shfl_down(cs, off, 64);
    cq += __shfl_down(cq, off, 64);
  }
  if ((tid & 63) == 0) { wcs[tid >> 6] = cs; wcq[tid >> 6] = cq; }
  __syncthreads();
  if (tid == 0) {
    float CS = wcs[0] + wcs[1] + wcs[2] + wcs[3];
    float CQ = wcq[0] + wcq[1] + wcq[2] + wcq[3];
    float mu = CS * (1.f / NROWS);
    float var = CQ * (1.f / NROWS) - mu * mu;
    float sc = g[j] * rsqrtf(var + 1e-5f);
    scale[j] = sc;
    shift[j] = be[j] - mu * sc;
  }
}

// ---------------------------------------------------------------------------
// K3 (FROZEN from R12)
// ---------------------------------------------------------------------------
__global__ __launch_bounds__(256, 4) void k_encode(
    const ushort_t* __restrict__ H1, const float* __restrict__ scale1,
    const float* __restrict__ shift1, const ushort_t* __restrict__ W2t,
    const float* __restrict__ b2, const ushort_t* __restrict__ CBb,
    const float* __restrict__ cn, int* __restrict__ topics,
    int* __restrict__ counts, float* __restrict__ Zloss)
{
  __shared__ ushort_t Hb[64 * 128];
  __shared__ float Zt[64 * 33];
  __shared__ int hist[512];
  __shared__ float zsh;

  const int tid = threadIdx.x;
  const int lane = tid & 63;
  const int w = tid >> 6;
  const int lr = lane & 15;
  const int lk = lane >> 4;
  const int row0 = blockIdx.x * 64;

  hist[tid] = 0; hist[tid + 256] = 0;
  if (tid == 0) zsh = 0.f;

  {
    const int c8 = (tid & 15) * 8;
    const int rb = tid >> 4;
    float sc[8], sh[8];
    {
      float4 a = *(const float4*)(scale1 + c8);
      float4 b = *(const float4*)(scale1 + c8 + 4);
      sc[0]=a.x; sc[1]=a.y; sc[2]=a.z; sc[3]=a.w; sc[4]=b.x; sc[5]=b.y; sc[6]=b.z; sc[7]=b.w;
      float4 e = *(const float4*)(shift1 + c8);
      float4 f = *(const float4*)(shift1 + c8 + 4);
      sh[0]=e.x; sh[1]=e.y; sh[2]=e.z; sh[3]=e.w; sh[4]=f.x; sh[5]=f.y; sh[6]=f.z; sh[7]=f.w;
    }
#pragma unroll
    for (int j = 0; j < 4; ++j) {
      int r = rb + 16 * j;
      uint4 v = *(const uint4*)(H1 + (size_t)(row0 + r) * HDIM + c8);
      uint_t u[4] = {v.x, v.y, v.z, v.w};
      uint4 o;
      uint_t* op = (uint_t*)&o;
#pragma unroll
      for (int m = 0; m < 4; ++m) {
        float f0 = fmaxf(bflo(u[m]) * sc[2*m]   + sh[2*m],   0.f);
        float f1 = fmaxf(bfhi(u[m]) * sc[2*m+1] + sh[2*m+1], 0.f);
        op[m] = pk2(f0, f1);
      }
      *(uint4*)(Hb + r * 128 + ((((c8 >> 3) ^ (r & 7))) << 3)) = o;
    }
  }
  __syncthreads();

  float zn4[4];
  {
    s16x8 af[4];
#pragma unroll
    for (int kt = 0; kt < 4; ++kt) {
      int m = w * 16 + lr;
      int b = kt * 4 + lk;
      af[kt] = *(const s16x8*)(Hb + m * 128 + ((b ^ (m & 7)) << 3));
    }
    f32x4 zacc[2];
    zacc[0] = (f32x4)(0.f); zacc[1] = (f32x4)(0.f);
#pragma unroll
    for (int ct = 0; ct < 2; ++ct)
#pragma unroll
      for (int kt = 0; kt < 4; ++kt) {
        s16x8 bf = *(const s16x8*)(W2t + (ct * 16 + lr) * 128 + kt * 32 + lk * 8);
        zacc[ct] = __builtin_amdgcn_mfma_f32_16x16x32_bf16(af[kt], bf, zacc[ct], 0, 0, 0);
      }
    float bias0 = b2[lr], bias1 = b2[16 + lr];
    float s4[4];
#pragma unroll
    for (int r = 0; r < 4; ++r) {
      float z0 = zacc[0][r] + bias0;
      float z1 = zacc[1][r] + bias1;
      int row = w * 16 + lk * 4 + r;
      Zt[row * 33 + lr] = z0;
      Zt[row * 33 + 16 + lr] = z1;
      s4[r] = z0 * z0 + z1 * z1;
    }
#pragma unroll
    for (int m = 1; m < 16; m <<= 1) {
#pragma unroll
      for (int r = 0; r < 4; ++r) s4[r] += __shfl_xor(s4[r], m, 64);
    }
#pragma unroll
    for (int r = 0; r < 4; ++r) zn4[r] = s4[r];
  }
  __syncthreads();

  {
    s16x8 za;
    {
      const float* zp = Zt + (w * 16 + lr) * 33 + lk * 8;
      float4 q0 = *(const float4*)(zp);
      float4 q1 = *(const float4*)(zp + 4);
      union { s16x8 v; uint_t u[4]; } zu;
      zu.u[0] = pk2(q0.x, q0.y);
      zu.u[1] = pk2(q0.z, q0.w);
      zu.u[2] = pk2(q1.x, q1.y);
      zu.u[3] = pk2(q1.z, q1.w);
      za = zu.v;
    }
    float minv[4] = {3.4e38f, 3.4e38f, 3.4e38f, 3.4e38f};
    int mini[4] = {0, 0, 0, 0};
#pragma unroll 4
    for (int t = 0; t < 32; ++t) {
      const int c = t * 16 + lr;
      s16x8 cb = *(const s16x8*)(CBb + c * 32 + lk * 8);
      f32x4 dot = __builtin_amdgcn_mfma_f32_16x16x32_bf16(za, cb, (f32x4)(0.f), 0, 0, 0);
      float cnv = cn[c];
#pragma unroll
      for (int r = 0; r < 4; ++r) {
        float d = fmaf(-2.f, dot[r], cnv);
        if (d < minv[r]) { minv[r] = d; mini[r] = c; }
      }
    }
#pragma unroll
    for (int m = 1; m < 16; m <<= 1) {
#pragma unroll
      for (int r = 0; r < 4; ++r) {
        float ov = __shfl_xor(minv[r], m, 64);
        int   oi = __shfl_xor(mini[r], m, 64);
        if (ov < minv[r] || (ov == minv[r] && oi < mini[r])) { minv[r] = ov; mini[r] = oi; }
      }
    }
    if (lr == 0) {
      float part = 0.f;
#pragma unroll
      for (int r = 0; r < 4; ++r) {
        int row = row0 + w * 16 + lk * 4 + r;
        topics[row] = mini[r];
        atomicAdd(&hist[mini[r]], 1);
        part += minv[r] + zn4[r];
      }
      atomicAdd(&zsh, part);
    }
  }
  __syncthreads();
  {
    int h0 = hist[tid], h1 = hist[tid + 256];
    if (h0) atomicAdd(&counts[tid], h0);
    if (h1) atomicAdd(&counts[tid + 256], h1);
    if (tid == 0) atomicAdd(Zloss, zsh);
  }
}

// Decoder BN params from topic histogram (exact batch stats)
__global__ void k_bn2(const int* __restrict__ counts, const float* __restrict__ T,
    const float* __restrict__ g, const float* __restrict__ be,
    float* __restrict__ scale2, float* __restrict__ shift2)
{
  __shared__ float cw[512];
  int j = threadIdx.x;  // 128
  for (int i = j; i < 512; i += 128) cw[i] = (float)counts[i];
  __syncthreads();
  float s = 0.f, ss = 0.f;
  for (int k = 0; k < KCODES; ++k) {
    float t = T[k * HDIM + j];
    float c = cw[k];
    s += c * t; ss += c * t * t;
  }
  float mu = s * (1.f / NROWS);
  float var = ss * (1.f / NROWS) - mu * mu;
  float sc = g[j] * rsqrtf(var + 1e-5f);
  scale2[j] = sc;
  shift2[j] = be[j] - mu * sc;
}

// U = relu(bn(T)) @ dec_W2 + dec_b2   [512 x 512]
__global__ __launch_bounds__(256) void k_U(const float* __restrict__ T,
    const float* __restrict__ scale2, const float* __restrict__ shift2,
    const float* __restrict__ dW2, const float* __restrict__ db2,
    float* __restrict__ U)
{
  __shared__ float Tb[128];
  const int tid = threadIdx.x;
  const int k = blockIdx.x >> 1;
  const int c = (blockIdx.x & 1) * 256 + tid;
  if (tid < 128) Tb[tid] = fmaxf(T[k * HDIM + tid] * scale2[tid] + shift2[tid], 0.f);
  __syncthreads();
  float acc = db2[c];
#pragma unroll 8
  for (int j = 0; j < HDIM; ++j) acc += Tb[j] * dW2[j * 512 + c];
  U[(size_t)k * 512 + c] = acc;
}

// ---------------------------------------------------------------------------
// Reconstruction (FROZEN from R12)
// ---------------------------------------------------------------------------
__global__ __launch_bounds__(256, 4) void k_recon(
    const float* __restrict__ X, const float* __restrict__ U,
    const int* __restrict__ topics, float* __restrict__ Rsum)
{
  __shared__ float bsum;
  const int tid = threadIdx.x;
  if (tid == 0) bsum = 0.f;
  __syncthreads();
  const int lane = tid & 63;
  const int wave = blockIdx.x * 4 + (tid >> 6);    // 0..4095
  const size_t base = (size_t)wave * 32;

  int tv = (lane < 32) ? topics[base + lane] : 0;
  const float4* Xb = (const float4*)(X + base * 512);
  float acc = 0.f;
#pragma unroll 4
  for (int i = 0; i < 32; ++i) {
    int t = __shfl(tv, i, 64);
    const float4* xr = Xb + i * 128;
    const float4* ur = (const float4*)(U + (size_t)t * 512);
    float4 x0 = xr[lane],      u0 = ur[lane];
    float4 x1 = xr[lane + 64], u1 = ur[lane + 64];
    float d;
    d = x0.x - u0.x; acc += d * d;
    d = x0.y - u0.y; acc += d * d;
    d = x0.z - u0.z; acc += d * d;
    d = x0.w - u0.w; acc += d * d;
    d = x1.x - u1.x; acc += d * d;
    d = x1.y - u1.y; acc += d * d;
    d = x1.z - u1.z; acc += d * d;
    d = x1.w - u1.w; acc += d * d;
  }
#pragma unroll
  for (int off = 32; off > 0; off >>= 1) acc += __shfl_down(acc, off, 64);
  if (lane == 0) atomicAdd(&bsum, acc);
  __syncthreads();
  if (tid == 0) atomicAdd(Rsum, bsum);
}

__global__ void k_final(const float* __restrict__ Zloss,
                        const float* __restrict__ Rsum, float* __restrict__ out)
{
  // C_loss == Z_loss in forward (stop_gradient is identity forward)
  out[0] = 2.f * Zloss[0] + sqrtf(Rsum[0]);
}

// ---------------------------------------------------------------------------
// Workspace layout (bytes):
//   0         H1 bf16            [N*128]      33,554,432
//   33554432  topics int32       [N]             524,288
//   34078720  accumulators (zeroed by k_prep):
//               counts[512]i32@8192, Zloss@10240, Rsum@10244
//   34092032  scale1[128]+shift1[128]
//   34093056  cn[512] f32
//   34095104  T[512*128] f32                   262,144   -> 34,357,248
//   34357248  scale2[128]+shift2[128]
//   34358272  U[512*512] f32                 1,048,576   -> 35,406,848
//               (W1f bf16 131,072 aliases U start; disjoint lifetime)
//   35406848  W2t bf16 [32][128]                 8,192   -> 35,415,040
//   35415040  CBb bf16 [512][32]                32,768   -> 35,447,808
//   36700160  colsump f32 [4096][128]        2,097,152   -> 38,797,312
//   38797312  colsumsqp f32 [4096][128]      2,097,152   -> 40,894,464
// ---------------------------------------------------------------------------
extern "C" void kernel_launch(void* const* d_in, const int* in_sizes, int n_in,
                              void* d_out, int out_size, void* d_ws, size_t ws_size,
                              hipStream_t stream) {
  const float* X    = (const float*)d_in[0];
  const float* eW1  = (const float*)d_in[1];
  const float* eb1  = (const float*)d_in[2];
  const float* eg1  = (const float*)d_in[3];
  const float* ebe1 = (const float*)d_in[4];
  const float* eW2  = (const float*)d_in[5];
  const float* eb2  = (const float*)d_in[6];
  const float* CB   = (const float*)d_in[7];
  const float* dW1  = (const float*)d_in[8];
  const float* db1  = (const float*)d_in[9];
  const float* dg1  = (const float*)d_in[10];
  const float* dbe1 = (const float*)d_in[11];
  const float* dW2  = (const float*)d_in[12];
  const float* db2  = (const float*)d_in[13];
  float* out = (float*)d_out;

  char* wsb = (char*)d_ws;
  ushort_t* H1    = (ushort_t*)wsb;
  int* topics     = (int*)(wsb + 33554432);
  float* accz     = (float*)(wsb + 34078720);
  int* counts     = (int*)(wsb + 34078720 + 8192);
  float* Zloss    = (float*)(wsb + 34078720 + 10240);
  float* Rsum     = Zloss + 1;
  float* scale1   = (float*)(wsb + 34092032);
  float* shift1   = scale1 + 128;
  float* cn       = (float*)(wsb + 34093056);
  float* T        = (float*)(wsb + 34095104);
  float* scale2   = (float*)(wsb + 34357248);
  float* shift2   = scale2 + 128;
  float* U        = (float*)(wsb + 34358272);
  ushort_t* W1f   = (ushort_t*)(wsb + 34358272);  // aliases U (disjoint lifetime)
  ushort_t* W2t   = (ushort_t*)(wsb + 35406848);
  ushort_t* CBb   = (ushort_t*)(wsb + 35415040);
  float* colsump  = (float*)(wsb + 36700160);
  float* colsumsqp= (float*)(wsb + 38797312);

  k_prep<<<256, 256, 0, stream>>>(eW1, eW2, CB, dW1, db1, W1f, W2t, CBb, cn, T,
                                  accz);
  k_gemm1<<<NROWS / 32, 256, 0, stream>>>(X, W1f, eb1, H1, colsump, colsumsqp);
  k_bn1<<<128, 256, 0, stream>>>(colsump, colsumsqp, eg1, ebe1, scale1, shift1);
  k_encode<<<NROWS / 64, 256, 0, stream>>>(H1, scale1, shift1, W2t, eb2, CBb, cn,
                                           topics, counts, Zloss);
  k_bn2<<<1, 128, 0, stream>>>(counts, T, dg1, dbe1, scale2, shift2);
  k_U<<<KCODES * 2, 256, 0, stream>>>(T, scale2, shift2, dW2, db2, U);
  k_recon<<<1024, 256, 0, stream>>>(X, U, topics, Rsum);
  k_final<<<1, 1, 0, stream>>>(Zloss, Rsum, out);
}